// Round 5
// baseline (318.247 us; speedup 1.0000x reference)
//
#include <hip/hip_runtime.h>
#include <hip/hip_bf16.h>

// ---------------- problem constants ----------------
#define NTOK   8192
#define TOPK   2
#define NROWS  (NTOK*TOPK)      // 16384
#define NEXP   8
#define KDIM   1024             // inner (INTER)
#define NDIM   2048             // output (HIDDEN)
#define MAX_TILES 136           // sum ceil(cnt_e/128) <= 128+8
#define NTILE  (NDIM/128)       // 16
#define GRID_G (MAX_TILES*NTILE) // 2176, divisible by 8

typedef __bf16 bf16_t;
typedef __bf16 bf16x8 __attribute__((ext_vector_type(8)));
typedef __bf16 bf16x4 __attribute__((ext_vector_type(4)));
typedef float  f32x4  __attribute__((ext_vector_type(4)));

static_assert(sizeof(bf16x8) == 16, "bf16x8 must be 16B");

// ---------------- ws layout (bytes) ----------------
#define OFF_TW    ((size_t)0)                    // 16384 f32 = 64KB
#define OFF_CNT   ((size_t)(1<<16))              // 8 i32
#define OFF_WL    ((size_t)((1<<16) + 1024))     // 136 * int4
#define OFF_RL    ((size_t)(1<<18))              // 8*16384 i32 = 512KB
#define OFF_WB    ((size_t)(1<<20))              // 8*2048*1024 bf16 = 32MB
#define OFF_SCR   ((size_t)(34u<<20))            // 16384*2048 bf16 = 64MB
#define NEED_BF16 (OFF_SCR + (size_t)NROWS*NDIM*2)   // ~98MB

// ---------------- 1. routing: softmax + top2 + bucket (fused) ----------------
__global__ void routing_kernel(const float* __restrict__ logits,
                               float* __restrict__ tw,
                               int* __restrict__ cnt, int* __restrict__ rowlist) {
  int t = blockIdx.x * blockDim.x + threadIdx.x;
  if (t >= NTOK) return;
  float4 a = *(const float4*)(logits + (size_t)t*NEXP);
  float4 b = *(const float4*)(logits + (size_t)t*NEXP + 4);
  float l[8] = {a.x, a.y, a.z, a.w, b.x, b.y, b.z, b.w};
  float m = l[0];
#pragma unroll
  for (int i = 1; i < 8; i++) m = fmaxf(m, l[i]);
  float p[8], s = 0.f;
#pragma unroll
  for (int i = 0; i < 8; i++) { p[i] = __expf(l[i] - m); s += p[i]; }
  int e0 = 0; float b0 = p[0];
#pragma unroll
  for (int i = 1; i < 8; i++) if (p[i] > b0) { b0 = p[i]; e0 = i; }
  int e1 = (e0 == 0) ? 1 : 0; float b1 = p[e1];
#pragma unroll
  for (int i = 0; i < 8; i++) if (i != e0 && p[i] > b1) { b1 = p[i]; e1 = i; }
  float inv = 1.f / s;
  tw[2*t]   = b0 * inv;
  tw[2*t+1] = b1 * inv;
  int pos0 = atomicAdd(&cnt[e0], 1);
  rowlist[(size_t)e0*NROWS + pos0] = 2*t;
  int pos1 = atomicAdd(&cnt[e1], 1);
  rowlist[(size_t)e1*NROWS + pos1] = 2*t + 1;
}

// ---------------- 2. worklist of (expert,row-tile of 128) ----------------
__global__ void build_wl_kernel(const int* __restrict__ cnt, int4* __restrict__ wl) {
  __shared__ int base[NEXP+1];
  if (threadIdx.x == 0) {
    int acc = 0;
    for (int e = 0; e < NEXP; e++) { base[e] = acc; acc += (cnt[e] + 127) >> 7; }
    base[NEXP] = acc;
  }
  __syncthreads();
  int t = threadIdx.x;
  if (t < MAX_TILES) {
    int4 v = {0, 0, 0, 0};
#pragma unroll
    for (int e = 0; e < NEXP; e++) {
      if (t >= base[e] && t < base[e+1]) {
        int rb = (t - base[e]) << 7;
        int c  = cnt[e];
        v.x = e; v.y = rb; v.z = (c - rb < 128) ? (c - rb) : 128;
      }
    }
    wl[t] = v;
  }
}

// ---------------- 3. convert+transpose w -> bf16 [E][N][K] ----------------
__global__ void cvt_w_kernel(const float* __restrict__ w, bf16_t* __restrict__ wb) {
  __shared__ float tf[64*65];
  int e  = blockIdx.z;
  int n0 = blockIdx.x * 64;
  int k0 = blockIdx.y * 64;
  int t  = threadIdx.x;
  const float* src = w + (size_t)e*KDIM*NDIM + (size_t)k0*NDIM + n0;
#pragma unroll
  for (int i = 0; i < 4; i++) {
    int idx = t + i*256;
    int kr  = idx >> 4;
    int nc4 = (idx & 15) * 4;
    float4 v = *(const float4*)(src + (size_t)kr*NDIM + nc4);
    tf[kr*65 + nc4+0] = v.x; tf[kr*65 + nc4+1] = v.y;
    tf[kr*65 + nc4+2] = v.z; tf[kr*65 + nc4+3] = v.w;
  }
  __syncthreads();
  bf16_t* dst = wb + (size_t)e*NDIM*KDIM + (size_t)n0*KDIM + k0;
#pragma unroll
  for (int i = 0; i < 2; i++) {
    int idx = t + i*256;
    int nr  = idx >> 3;
    int kc  = (idx & 7) * 8;
    bf16x8 o;
#pragma unroll
    for (int j = 0; j < 8; j++) o[j] = (bf16_t)tf[(kc+j)*65 + nr];
    *(bf16x8*)(dst + (size_t)nr*KDIM + kc) = o;
  }
}

// ---------------- 4. grouped GEMM: 128x128, BK=32, reg-staged pipeline -------
// LDS per buf: A [128 rows][40 bf16] (80B-pad) + B same. 2 buffers = 40960 B.
// Thread t stages row t>>1, k-half (t&1)*16: A from fp32 x (cvt in reg),
// B from bf16 wb. Loads for tile t+1 issue before tile t's MFMAs (T14 split).
#define ABUF(c) ((c)*20480)
#define BBUF(c) ((c)*20480 + 10240)

#define STEP(CUR, STAGE) do {                                                  \
    bf16x8 af[4], bfv[4];                                                      \
    _Pragma("unroll") for (int mi = 0; mi < 4; mi++)                           \
      af[mi] = *(const bf16x8*)&smem[ABUF(CUR) + aoff + mi*1280];              \
    _Pragma("unroll") for (int ni = 0; ni < 4; ni++)                           \
      bfv[ni] = *(const bf16x8*)&smem[BBUF(CUR) + boff + ni*1280];             \
    float4 la0, la1, la2, la3; bf16x8 lb0, lb1;                                \
    if (STAGE) {                                                               \
      la0 = *(const float4*)(gA);      la1 = *(const float4*)(gA + 4);         \
      la2 = *(const float4*)(gA + 8);  la3 = *(const float4*)(gA + 12);        \
      lb0 = *(const bf16x8*)(gB);      lb1 = *(const bf16x8*)(gB + 8);         \
      gA += 32; gB += 32;                                                      \
    }                                                                          \
    _Pragma("unroll") for (int mi = 0; mi < 4; mi++)                           \
      _Pragma("unroll") for (int ni = 0; ni < 4; ni++)                         \
        acc[mi][ni] = __builtin_amdgcn_mfma_f32_16x16x32_bf16(                 \
            af[mi], bfv[ni], acc[mi][ni], 0, 0, 0);                            \
    if (STAGE) {                                                               \
      bf16x8 aw0 = { (bf16_t)la0.x, (bf16_t)la0.y, (bf16_t)la0.z, (bf16_t)la0.w, \
                     (bf16_t)la1.x, (bf16_t)la1.y, (bf16_t)la1.z, (bf16_t)la1.w }; \
      bf16x8 aw1 = { (bf16_t)la2.x, (bf16_t)la2.y, (bf16_t)la2.z, (bf16_t)la2.w, \
                     (bf16_t)la3.x, (bf16_t)la3.y, (bf16_t)la3.z, (bf16_t)la3.w }; \
      *(bf16x8*)&smem[ABUF((CUR)^1) + wro]      = aw0;                         \
      *(bf16x8*)&smem[ABUF((CUR)^1) + wro + 16] = aw1;                         \
      *(bf16x8*)&smem[BBUF((CUR)^1) + wro]      = lb0;                         \
      *(bf16x8*)&smem[BBUF((CUR)^1) + wro + 16] = lb1;                         \
    }                                                                          \
    __syncthreads();                                                           \
  } while (0)

template <int MODE>
__global__ __launch_bounds__(256, 3)
void gemm_kernel(const float*  __restrict__ x,      // [NROWS][KDIM] fp32
                 const bf16_t* __restrict__ wb,     // [NEXP][NDIM][KDIM]
                 const int*    __restrict__ rowlist,
                 const int4*   __restrict__ wl,
                 const float*  __restrict__ tw,
                 bf16_t*       __restrict__ scrb,
                 float*        __restrict__ outp) {
  __shared__ char smem[40960];

  int bid = blockIdx.x;
  int lin = (bid & 7) * (GRID_G/8) + (bid >> 3);
  int xt  = lin & (NTILE-1);
  int yt  = lin / NTILE;

  int4 wle = wl[yt];
  const int nrows = wle.z;
  if (nrows <= 0) return;
  const int e  = wle.x;
  const int n0 = xt * 128;

  const int t    = threadIdx.x;
  const int lane = t & 63;
  const int wv   = t >> 6;

  // staging: thread stages row t>>1, k-half t&1 (16 elems)
  const int srow = t >> 1;
  const int sj   = t & 1;
  const int wro  = srow*80 + sj*32;              // LDS byte offset (write)
  const int* rl = rowlist + (size_t)e*NROWS + wle.y;
  int ra = rl[srow < nrows ? srow : nrows-1];
  const float*  gA = x  + (size_t)ra*KDIM + sj*16;
  const bf16_t* gB = wb + ((size_t)e*NDIM + n0 + srow)*KDIM + sj*16;

  // fragment read bases
  const int wr = (wv >> 1) * 64;
  const int wc = (wv & 1) * 64;
  const int lr = lane & 15;
  const int l4 = lane >> 4;
  const int aoff = (wr + lr)*80 + l4*16;
  const int boff = (wc + lr)*80 + l4*16;

  f32x4 acc[4][4] = {};

  // prologue: stage tile 0 into buf0
  {
    float4 la0 = *(const float4*)(gA);     float4 la1 = *(const float4*)(gA + 4);
    float4 la2 = *(const float4*)(gA + 8); float4 la3 = *(const float4*)(gA + 12);
    bf16x8 lb0 = *(const bf16x8*)(gB);     bf16x8 lb1 = *(const bf16x8*)(gB + 8);
    gA += 32; gB += 32;
    bf16x8 aw0 = { (bf16_t)la0.x, (bf16_t)la0.y, (bf16_t)la0.z, (bf16_t)la0.w,
                   (bf16_t)la1.x, (bf16_t)la1.y, (bf16_t)la1.z, (bf16_t)la1.w };
    bf16x8 aw1 = { (bf16_t)la2.x, (bf16_t)la2.y, (bf16_t)la2.z, (bf16_t)la2.w,
                   (bf16_t)la3.x, (bf16_t)la3.y, (bf16_t)la3.z, (bf16_t)la3.w };
    *(bf16x8*)&smem[ABUF(0) + wro]      = aw0;
    *(bf16x8*)&smem[ABUF(0) + wro + 16] = aw1;
    *(bf16x8*)&smem[BBUF(0) + wro]      = lb0;
    *(bf16x8*)&smem[BBUF(0) + wro + 16] = lb1;
  }
  __syncthreads();

  // 32 K-steps: t=0..29 in loop, stages t+1; then t=30 stages 31; t=31 no stage
#pragma unroll 1
  for (int kt = 0; kt < 15; ++kt) {
    STEP(0, true);
    STEP(1, true);
  }
  STEP(0, true);
  STEP(1, false);

  // epilogue: C/D col = lane&15, row = l4*4 + jj
#pragma unroll
  for (int mi = 0; mi < 4; mi++) {
#pragma unroll
    for (int jj = 0; jj < 4; jj++) {
      int rb = wr + mi*16 + l4*4 + jj;
      if (rb < nrows) {
        int r = rl[rb];
        float s = tw[r];
        int col0 = n0 + wc + lr;
        if (MODE == 1) {
          bf16_t* dst = scrb + (size_t)r*NDIM + col0;
#pragma unroll
          for (int n = 0; n < 4; n++) dst[n*16] = (bf16_t)(acc[mi][n][jj] * s);
        } else {
          float* dst = outp + (size_t)(r >> 1)*NDIM + col0;
#pragma unroll
          for (int n = 0; n < 4; n++) atomicAdd(dst + n*16, acc[mi][n][jj] * s);
        }
      }
    }
  }
}

// ---------------- 5. pair reduce (bf16 scratch -> fp32 out), 32B loads -------
__global__ void reduce_bf16_kernel(const bf16_t* __restrict__ scr, float* __restrict__ out) {
  int i = blockIdx.x * blockDim.x + threadIdx.x;   // one bf16x8-pair per thread
  int tk = i >> 8;                 // NDIM/8 = 256 chunks per row
  int h  = (i & 255) * 8;
  bf16x8 a = *(const bf16x8*)(scr + ((size_t)2*tk    )*NDIM + h);
  bf16x8 b = *(const bf16x8*)(scr + ((size_t)2*tk + 1)*NDIM + h);
  float4 o0 = { (float)a[0]+(float)b[0], (float)a[1]+(float)b[1],
                (float)a[2]+(float)b[2], (float)a[3]+(float)b[3] };
  float4 o1 = { (float)a[4]+(float)b[4], (float)a[5]+(float)b[5],
                (float)a[6]+(float)b[6], (float)a[7]+(float)b[7] };
  float* dst = out + (size_t)tk*NDIM + h;
  *(float4*)(dst)     = o0;
  *(float4*)(dst + 4) = o1;
}

// ---------------- launch ----------------
extern "C" void kernel_launch(void* const* d_in, const int* in_sizes, int n_in,
                              void* d_out, int out_size, void* d_ws, size_t ws_size,
                              hipStream_t stream) {
  const float* x      = (const float*)d_in[0];
  const float* w      = (const float*)d_in[1];
  const float* logits = (const float*)d_in[2];
  float* out = (float*)d_out;

  char* ws = (char*)d_ws;
  float*  tw      = (float*)(ws + OFF_TW);
  int*    cnt     = (int*)  (ws + OFF_CNT);
  int4*   wl      = (int4*) (ws + OFF_WL);
  int*    rowlist = (int*)  (ws + OFF_RL);
  bf16_t* wb      = (bf16_t*)(ws + OFF_WB);
  bf16_t* scrb    = (bf16_t*)(ws + OFF_SCR);

  hipMemsetAsync(cnt, 0, NEXP * sizeof(int), stream);
  routing_kernel<<<NTOK/256, 256, 0, stream>>>(logits, tw, cnt, rowlist);
  build_wl_kernel<<<1, 256, 0, stream>>>(cnt, wl);
  cvt_w_kernel<<<dim3(NDIM/64, KDIM/64, NEXP), 256, 0, stream>>>(w, wb);

  if (ws_size >= NEED_BF16) {
    gemm_kernel<1><<<GRID_G, 256, 0, stream>>>(x, wb, rowlist, wl, tw, scrb, nullptr);
    reduce_bf16_kernel<<<NTOK*NDIM/8/256, 256, 0, stream>>>(scrb, out);
  } else {
    hipMemsetAsync(d_out, 0, (size_t)NTOK * NDIM * sizeof(float), stream);
    gemm_kernel<2><<<GRID_G, 256, 0, stream>>>(x, wb, rowlist, wl, tw, nullptr, out);
  }
}